// Round 7
// baseline (130.354 us; speedup 1.0000x reference)
//
#include <hip/hip_runtime.h>
#include <math.h>

#define NJ  16
#define BLK 256

typedef float fx4 __attribute__((ext_vector_type(4)));

// Affine 3x4: m[0..8] = row-major R, m[9..11] = p.
struct Mat { float m[12]; };

// C = A @ B (apply B then A): matches T_new = T_old @ A_j as mul(earlier, later).
__device__ __forceinline__ Mat mul(const Mat& A, const Mat& B) {
    Mat C;
    #pragma unroll
    for (int r = 0; r < 3; ++r) {
        float a0 = A.m[3*r+0], a1 = A.m[3*r+1], a2 = A.m[3*r+2];
        C.m[3*r+0] = a0*B.m[0] + a1*B.m[3] + a2*B.m[6];
        C.m[3*r+1] = a0*B.m[1] + a1*B.m[4] + a2*B.m[7];
        C.m[3*r+2] = a0*B.m[2] + a1*B.m[5] + a2*B.m[8];
        C.m[9+r]   = a0*B.m[9] + a1*B.m[10] + a2*B.m[11] + A.m[9+r];
    }
    return C;
}

// srodrigues for joint j; twist row loaded on demand (L1-resident, 384 B total).
__device__ __forceinline__ Mat buildA(const float* __restrict__ twist, int j, float qj) {
    const float2* t2 = reinterpret_cast<const float2*>(twist) + 3 * j;
    float2 ta = t2[0], tb = t2[1], tc = t2[2];
    float w0 = ta.x, w1 = ta.y, w2 = tb.x;
    float v0 = tb.y, v1 = tc.x, v2 = tc.y;
    float theta = sqrtf(w0*w0 + w1*w1 + w2*w2) + 1e-12f;
    float inv   = __builtin_amdgcn_rcpf(theta);
    float wn0 = w0*inv, wn1 = w1*inv, wn2 = w2*inv;
    float vn0 = v0*inv, vn1 = v1*inv, vn2 = v2*inv;
    float qt  = qj * theta;
    float s   = __sinf(qt);
    float cth = __cosf(qt);
    float c   = 1.0f - cth;
    float ts  = qt - s;
    Mat A;
    A.m[0] = cth + c*wn0*wn0;   A.m[1] = c*wn0*wn1 - s*wn2; A.m[2] = c*wn0*wn2 + s*wn1;
    A.m[3] = c*wn1*wn0 + s*wn2; A.m[4] = cth + c*wn1*wn1;   A.m[5] = c*wn1*wn2 - s*wn0;
    A.m[6] = c*wn2*wn0 - s*wn1; A.m[7] = c*wn2*wn1 + s*wn0; A.m[8] = cth + c*wn2*wn2;
    float cx0 = wn1*vn2 - wn2*vn1;
    float cx1 = wn2*vn0 - wn0*vn2;
    float cx2 = wn0*vn1 - wn1*vn0;
    float d   = wn0*vn0 + wn1*vn1 + wn2*vn2;
    float td  = ts * d;
    A.m[9]  = s*vn0 + c*cx0 + td*wn0;
    A.m[10] = s*vn1 + c*cx1 + td*wn1;
    A.m[11] = s*vn2 + c*cx2 + td*wn2;
    return A;
}

// 4 lanes per batch element; lane handles 4 consecutive joints; quad scan.
__global__ __launch_bounds__(BLK) void poe_fwd(
    const float* __restrict__ q,        // B x 16
    const float* __restrict__ twist,    // 16 x 6 (uniform)
    const float* __restrict__ init_p,   // 3
    const float* __restrict__ init_rpy, // 3
    float* __restrict__ outT,           // B x 16
    float* __restrict__ outTw,          // B x 96
    int nb)
{
    const int g    = blockIdx.x * BLK + threadIdx.x;   // global lane
    const int e    = g >> 2;                           // batch element
    const int s    = g & 3;                            // segment (joints 4s..4s+3)
    const int lane = threadIdx.x & 63;
    if (e >= nb) return;

    float qk[4];
    {
        float4 t = reinterpret_cast<const float4*>(q)[(size_t)e * 4 + s];
        qk[0] = t.x; qk[1] = t.y; qk[2] = t.z; qk[3] = t.w;
    }

    // ---- phase 1: serial product of my segment ----
    Mat P = buildA(twist, 4*s + 0, qk[0]);
    #pragma unroll
    for (int k = 1; k < 4; ++k)
        P = mul(P, buildA(twist, 4*s + k, qk[k]));

    // ---- inclusive Kogge-Stone scan over the quad (steps 1, 2) ----
    #pragma unroll
    for (int step = 1; step < 4; step <<= 1) {
        const bool use = (s >= step);
        const int  src = use ? lane - step : lane;
        Mat T;
        #pragma unroll
        for (int i = 0; i < 12; ++i) T.m[i] = __shfl(P.m[i], src, 64);
        Mat M = mul(T, P);
        #pragma unroll
        for (int i = 0; i < 12; ++i) P.m[i] = use ? M.m[i] : P.m[i];
    }

    // ---- exclusive prefix = entry pose for my segment ----
    Mat pose;
    {
        const int src = (s == 0) ? lane : lane - 1;
        #pragma unroll
        for (int i = 0; i < 12; ++i) pose.m[i] = __shfl(P.m[i], src, 64);
        const float id[12] = {1,0,0, 0,1,0, 0,0,1, 0,0,0};
        #pragma unroll
        for (int i = 0; i < 12; ++i) pose.m[i] = (s == 0) ? id[i] : pose.m[i];
    }

    // ---- phase 2: tw_local for my 4 joints into a 24-float buffer ----
    float ob[24];
    #pragma unroll
    for (int k = 0; k < 4; ++k) {
        const int j = 4*s + k;
        const float2* t2 = reinterpret_cast<const float2*>(twist) + 3 * j;
        float2 ta = t2[0], tb = t2[1], tc = t2[2];
        float w0 = ta.x, w1 = ta.y, w2 = tb.x;
        float v0 = tb.y, v1 = tc.x, v2 = tc.y;
        float p0 = pose.m[9], p1 = pose.m[10], p2 = pose.m[11];
        float u0 = v0 - (p1*w2 - p2*w1);
        float u1 = v1 - (p2*w0 - p0*w2);
        float u2 = v2 - (p0*w1 - p1*w0);
        ob[6*k+0] = pose.m[0]*w0 + pose.m[3]*w1 + pose.m[6]*w2;
        ob[6*k+1] = pose.m[1]*w0 + pose.m[4]*w1 + pose.m[7]*w2;
        ob[6*k+2] = pose.m[2]*w0 + pose.m[5]*w1 + pose.m[8]*w2;
        ob[6*k+3] = pose.m[0]*u0 + pose.m[3]*u1 + pose.m[6]*u2;
        ob[6*k+4] = pose.m[1]*u0 + pose.m[4]*u1 + pose.m[7]*u2;
        ob[6*k+5] = pose.m[2]*u0 + pose.m[5]*u1 + pose.m[8]*u2;
        if (k < 3)
            pose = mul(pose, buildA(twist, j, qk[k]));
    }

    // ---- streaming (nontemporal) writeout: 96 B contiguous per thread ----
    {
        fx4* dst = reinterpret_cast<fx4*>(outTw) + (size_t)g * 6;
        #pragma unroll
        for (int i = 0; i < 6; ++i) {
            fx4 v = { ob[4*i+0], ob[4*i+1], ob[4*i+2], ob[4*i+3] };
            __builtin_nontemporal_store(v, dst + i);
        }
    }

    // ---- final: full-chain product from quad lane 3, apply T_init ----
    Mat F;
    {
        const int src = lane | 3;
        #pragma unroll
        for (int i = 0; i < 12; ++i) F.m[i] = __shfl(P.m[i], src, 64);
    }
    float rr = init_rpy[0], pt = init_rpy[1], yw = init_rpy[2];
    float sr = __sinf(rr), cr = __cosf(rr);
    float sp = __sinf(pt), cp = __cosf(pt);
    float sy = __sinf(yw), cy = __cosf(yw);
    float i00 = cy*cp, i01 = cy*sp*sr - sy*cr, i02 = cy*sp*cr + sy*sr;
    float i10 = sy*cp, i11 = sy*sp*sr + cy*cr, i12 = sy*sp*cr - cy*sr;
    float i20 = -sp,   i21 = cp*sr,            i22 = cp*cr;
    float ip0 = init_p[0], ip1 = init_p[1], ip2 = init_p[2];

    float r0 = (s == 0) ? F.m[0] : (s == 1) ? F.m[3] : F.m[6];
    float r1 = (s == 0) ? F.m[1] : (s == 1) ? F.m[4] : F.m[7];
    float r2 = (s == 0) ? F.m[2] : (s == 1) ? F.m[5] : F.m[8];
    float pr = (s == 0) ? F.m[9] : (s == 1) ? F.m[10] : F.m[11];
    fx4 row;
    row.x = r0*i00 + r1*i10 + r2*i20;
    row.y = r0*i01 + r1*i11 + r2*i21;
    row.z = r0*i02 + r1*i12 + r2*i22;
    row.w = r0*ip0 + r1*ip1 + r2*ip2 + pr;
    if (s == 3) { row.x = 0.f; row.y = 0.f; row.z = 0.f; row.w = 1.f; }

    __builtin_nontemporal_store(row, reinterpret_cast<fx4*>(outT) + (size_t)g);
}

extern "C" void kernel_launch(void* const* d_in, const int* in_sizes, int n_in,
                              void* d_out, int out_size, void* d_ws, size_t ws_size,
                              hipStream_t stream) {
    const float* q        = (const float*)d_in[0];
    const float* twist    = (const float*)d_in[1];
    const float* init_p   = (const float*)d_in[2];
    const float* init_rpy = (const float*)d_in[3];

    int nb = in_sizes[0] / NJ;   // B
    float* outT  = (float*)d_out;                  // B x 16 (4x4 matrices)
    float* outTw = outT + (size_t)nb * 16;         // B x 96 (Twistls)

    int threads = nb * 4;                          // 4 lanes per element
    int blocks  = (threads + BLK - 1) / BLK;
    poe_fwd<<<blocks, BLK, 0, stream>>>(q, twist, init_p, init_rpy, outT, outTw, nb);
}

// Round 8
// 61.632 us; speedup vs baseline: 2.1150x; 2.1150x over previous
//
#include <hip/hip_runtime.h>
#include <math.h>

#define NJ  16
#define BLK 256

// Affine 3x4: m[0..8] = row-major R, m[9..11] = p.
struct Mat { float m[12]; };

// C = A @ B (apply B then A): matches T_new = T_old @ A_j as mul(earlier, later).
__device__ __forceinline__ Mat mul(const Mat& A, const Mat& B) {
    Mat C;
    #pragma unroll
    for (int r = 0; r < 3; ++r) {
        float a0 = A.m[3*r+0], a1 = A.m[3*r+1], a2 = A.m[3*r+2];
        C.m[3*r+0] = a0*B.m[0] + a1*B.m[3] + a2*B.m[6];
        C.m[3*r+1] = a0*B.m[1] + a1*B.m[4] + a2*B.m[7];
        C.m[3*r+2] = a0*B.m[2] + a1*B.m[5] + a2*B.m[8];
        C.m[9+r]   = a0*B.m[9] + a1*B.m[10] + a2*B.m[11] + A.m[9+r];
    }
    return C;
}

// srodrigues for joint j; twist row loaded on demand (L1-resident, 384 B total).
__device__ __forceinline__ Mat buildA(const float* __restrict__ twist, int j, float qj) {
    const float2* t2 = reinterpret_cast<const float2*>(twist) + 3 * j;
    float2 ta = t2[0], tb = t2[1], tc = t2[2];
    float w0 = ta.x, w1 = ta.y, w2 = tb.x;
    float v0 = tb.y, v1 = tc.x, v2 = tc.y;
    float theta = sqrtf(w0*w0 + w1*w1 + w2*w2) + 1e-12f;
    float inv   = __builtin_amdgcn_rcpf(theta);
    float wn0 = w0*inv, wn1 = w1*inv, wn2 = w2*inv;
    float vn0 = v0*inv, vn1 = v1*inv, vn2 = v2*inv;
    float qt  = qj * theta;
    float s   = __sinf(qt);
    float cth = __cosf(qt);
    float c   = 1.0f - cth;
    float ts  = qt - s;
    Mat A;
    A.m[0] = cth + c*wn0*wn0;   A.m[1] = c*wn0*wn1 - s*wn2; A.m[2] = c*wn0*wn2 + s*wn1;
    A.m[3] = c*wn1*wn0 + s*wn2; A.m[4] = cth + c*wn1*wn1;   A.m[5] = c*wn1*wn2 - s*wn0;
    A.m[6] = c*wn2*wn0 - s*wn1; A.m[7] = c*wn2*wn1 + s*wn0; A.m[8] = cth + c*wn2*wn2;
    float cx0 = wn1*vn2 - wn2*vn1;
    float cx1 = wn2*vn0 - wn0*vn2;
    float cx2 = wn0*vn1 - wn1*vn0;
    float d   = wn0*vn0 + wn1*vn1 + wn2*vn2;
    float td  = ts * d;
    A.m[9]  = s*vn0 + c*cx0 + td*wn0;
    A.m[10] = s*vn1 + c*cx1 + td*wn1;
    A.m[11] = s*vn2 + c*cx2 + td*wn2;
    return A;
}

// 4 lanes per batch element; lane handles 4 consecutive joints; quad scan.
// launch_bounds(.,4): permit up to 128 VGPR so the ~55-float live set never
// spills (default compiler heuristic picked 68 and spilled/rematerialized).
__global__ __launch_bounds__(BLK, 4) void poe_fwd(
    const float* __restrict__ q,        // B x 16
    const float* __restrict__ twist,    // 16 x 6 (uniform)
    const float* __restrict__ init_p,   // 3
    const float* __restrict__ init_rpy, // 3
    float* __restrict__ outT,           // B x 16
    float* __restrict__ outTw,          // B x 96
    int nb)
{
    const int g    = blockIdx.x * BLK + threadIdx.x;   // global lane
    const int e    = g >> 2;                           // batch element
    const int s    = g & 3;                            // segment (joints 4s..4s+3)
    const int lane = threadIdx.x & 63;
    if (e >= nb) return;

    float qk[4];
    {
        float4 t = reinterpret_cast<const float4*>(q)[(size_t)e * 4 + s];
        qk[0] = t.x; qk[1] = t.y; qk[2] = t.z; qk[3] = t.w;
    }

    // ---- phase 1: serial product of my segment ----
    Mat P = buildA(twist, 4*s + 0, qk[0]);
    #pragma unroll
    for (int k = 1; k < 4; ++k)
        P = mul(P, buildA(twist, 4*s + k, qk[k]));

    // ---- inclusive Kogge-Stone scan over the quad (steps 1, 2) ----
    #pragma unroll
    for (int step = 1; step < 4; step <<= 1) {
        const bool use = (s >= step);
        const int  src = use ? lane - step : lane;
        Mat T;
        #pragma unroll
        for (int i = 0; i < 12; ++i) T.m[i] = __shfl(P.m[i], src, 64);
        Mat M = mul(T, P);
        #pragma unroll
        for (int i = 0; i < 12; ++i) P.m[i] = use ? M.m[i] : P.m[i];
    }

    // ---- exclusive prefix = entry pose for my segment ----
    Mat pose;
    {
        const int src = (s == 0) ? lane : lane - 1;
        #pragma unroll
        for (int i = 0; i < 12; ++i) pose.m[i] = __shfl(P.m[i], src, 64);
        const float id[12] = {1,0,0, 0,1,0, 0,0,1, 0,0,0};
        #pragma unroll
        for (int i = 0; i < 12; ++i) pose.m[i] = (s == 0) ? id[i] : pose.m[i];
    }

    // ---- phase 2: tw_local for my 4 joints, stored IMMEDIATELY (24 B/joint:
    //      one 16 B + one 8 B store; pieces of each 64 B line land within
    //      ~0.3 us, far inside L2 line lifetime -> full-line writebacks). ----
    float* twb = outTw + (size_t)g * 24;
    #pragma unroll
    for (int k = 0; k < 4; ++k) {
        const int j = 4*s + k;
        const float2* t2 = reinterpret_cast<const float2*>(twist) + 3 * j;
        float2 ta = t2[0], tb = t2[1], tc = t2[2];
        float w0 = ta.x, w1 = ta.y, w2 = tb.x;
        float v0 = tb.y, v1 = tc.x, v2 = tc.y;
        float p0 = pose.m[9], p1 = pose.m[10], p2 = pose.m[11];
        float u0 = v0 - (p1*w2 - p2*w1);
        float u1 = v1 - (p2*w0 - p0*w2);
        float u2 = v2 - (p0*w1 - p1*w0);
        float wl0 = pose.m[0]*w0 + pose.m[3]*w1 + pose.m[6]*w2;
        float wl1 = pose.m[1]*w0 + pose.m[4]*w1 + pose.m[7]*w2;
        float wl2 = pose.m[2]*w0 + pose.m[5]*w1 + pose.m[8]*w2;
        float vl0 = pose.m[0]*u0 + pose.m[3]*u1 + pose.m[6]*u2;
        float vl1 = pose.m[1]*u0 + pose.m[4]*u1 + pose.m[7]*u2;
        float vl2 = pose.m[2]*u0 + pose.m[5]*u1 + pose.m[8]*u2;
        *reinterpret_cast<float4*>(twb + 6*k)     = make_float4(wl0, wl1, wl2, vl0);
        *reinterpret_cast<float2*>(twb + 6*k + 4) = make_float2(vl1, vl2);
        if (k < 3)
            pose = mul(pose, buildA(twist, j, qk[k]));
    }

    // ---- final: full-chain product from quad lane 3, apply T_init ----
    Mat F;
    {
        const int src = lane | 3;
        #pragma unroll
        for (int i = 0; i < 12; ++i) F.m[i] = __shfl(P.m[i], src, 64);
    }
    float rr = init_rpy[0], pt = init_rpy[1], yw = init_rpy[2];
    float sr = __sinf(rr), cr = __cosf(rr);
    float sp = __sinf(pt), cp = __cosf(pt);
    float sy = __sinf(yw), cy = __cosf(yw);
    float i00 = cy*cp, i01 = cy*sp*sr - sy*cr, i02 = cy*sp*cr + sy*sr;
    float i10 = sy*cp, i11 = sy*sp*sr + cy*cr, i12 = sy*sp*cr - cy*sr;
    float i20 = -sp,   i21 = cp*sr,            i22 = cp*cr;
    float ip0 = init_p[0], ip1 = init_p[1], ip2 = init_p[2];

    float r0 = (s == 0) ? F.m[0] : (s == 1) ? F.m[3] : F.m[6];
    float r1 = (s == 0) ? F.m[1] : (s == 1) ? F.m[4] : F.m[7];
    float r2 = (s == 0) ? F.m[2] : (s == 1) ? F.m[5] : F.m[8];
    float pr = (s == 0) ? F.m[9] : (s == 1) ? F.m[10] : F.m[11];
    float4 row;
    row.x = r0*i00 + r1*i10 + r2*i20;
    row.y = r0*i01 + r1*i11 + r2*i21;
    row.z = r0*i02 + r1*i12 + r2*i22;
    row.w = r0*ip0 + r1*ip1 + r2*ip2 + pr;
    if (s == 3) row = make_float4(0.f, 0.f, 0.f, 1.f);

    reinterpret_cast<float4*>(outT)[(size_t)g] = row;
}

extern "C" void kernel_launch(void* const* d_in, const int* in_sizes, int n_in,
                              void* d_out, int out_size, void* d_ws, size_t ws_size,
                              hipStream_t stream) {
    const float* q        = (const float*)d_in[0];
    const float* twist    = (const float*)d_in[1];
    const float* init_p   = (const float*)d_in[2];
    const float* init_rpy = (const float*)d_in[3];

    int nb = in_sizes[0] / NJ;   // B
    float* outT  = (float*)d_out;                  // B x 16 (4x4 matrices)
    float* outTw = outT + (size_t)nb * 16;         // B x 96 (Twistls)

    int threads = nb * 4;                          // 4 lanes per element
    int blocks  = (threads + BLK - 1) / BLK;
    poe_fwd<<<blocks, BLK, 0, stream>>>(q, twist, init_p, init_rpy, outT, outTw, nb);
}

// Round 9
// 48.765 us; speedup vs baseline: 2.6731x; 1.2639x over previous
//
#include <hip/hip_runtime.h>
#include <math.h>

#define NJ  16
#define BLK 256
#define EPB 128   // elements per block = 2 iterations x 64 quads

// Affine 3x4: m[0..8] = row-major R, m[9..11] = p.
struct Mat { float m[12]; };

// C = A @ B (apply B then A): matches T_new = T_old @ A_j as mul(earlier, later).
__device__ __forceinline__ Mat mul(const Mat& A, const Mat& B) {
    Mat C;
    #pragma unroll
    for (int r = 0; r < 3; ++r) {
        float a0 = A.m[3*r+0], a1 = A.m[3*r+1], a2 = A.m[3*r+2];
        C.m[3*r+0] = a0*B.m[0] + a1*B.m[3] + a2*B.m[6];
        C.m[3*r+1] = a0*B.m[1] + a1*B.m[4] + a2*B.m[7];
        C.m[3*r+2] = a0*B.m[2] + a1*B.m[5] + a2*B.m[8];
        C.m[9+r]   = a0*B.m[9] + a1*B.m[10] + a2*B.m[11] + A.m[9+r];
    }
    return C;
}

// srodrigues for joint j; twist row loaded on demand (L1-resident, 384 B total).
__device__ __forceinline__ Mat buildA(const float* __restrict__ twist, int j, float qj) {
    const float2* t2 = reinterpret_cast<const float2*>(twist) + 3 * j;
    float2 ta = t2[0], tb = t2[1], tc = t2[2];
    float w0 = ta.x, w1 = ta.y, w2 = tb.x;
    float v0 = tb.y, v1 = tc.x, v2 = tc.y;
    float theta = sqrtf(w0*w0 + w1*w1 + w2*w2) + 1e-12f;
    float inv   = __builtin_amdgcn_rcpf(theta);
    float wn0 = w0*inv, wn1 = w1*inv, wn2 = w2*inv;
    float vn0 = v0*inv, vn1 = v1*inv, vn2 = v2*inv;
    float qt  = qj * theta;
    float s   = __sinf(qt);
    float cth = __cosf(qt);
    float c   = 1.0f - cth;
    float ts  = qt - s;
    Mat A;
    A.m[0] = cth + c*wn0*wn0;   A.m[1] = c*wn0*wn1 - s*wn2; A.m[2] = c*wn0*wn2 + s*wn1;
    A.m[3] = c*wn1*wn0 + s*wn2; A.m[4] = cth + c*wn1*wn1;   A.m[5] = c*wn1*wn2 - s*wn0;
    A.m[6] = c*wn2*wn0 - s*wn1; A.m[7] = c*wn2*wn1 + s*wn0; A.m[8] = cth + c*wn2*wn2;
    float cx0 = wn1*vn2 - wn2*vn1;
    float cx1 = wn2*vn0 - wn0*vn2;
    float cx2 = wn0*vn1 - wn1*vn0;
    float d   = wn0*vn0 + wn1*vn1 + wn2*vn2;
    float td  = ts * d;
    A.m[9]  = s*vn0 + c*cx0 + td*wn0;
    A.m[10] = s*vn1 + c*cx1 + td*wn1;
    A.m[11] = s*vn2 + c*cx2 + td*wn2;
    return A;
}

// 4 lanes per element, quad Kogge-Stone scan (R5 body), but each block now
// loops over 2 consecutive 64-element batches: 2048 blocks = 8/CU resident,
// halved dispatch count, store-drain amortized, iter1 compute overlaps
// iter0's in-flight stores.
__global__ __launch_bounds__(BLK) void poe_fwd(
    const float* __restrict__ q,        // B x 16
    const float* __restrict__ twist,    // 16 x 6 (uniform)
    const float* __restrict__ init_p,   // 3
    const float* __restrict__ init_rpy, // 3
    float* __restrict__ outT,           // B x 16
    float* __restrict__ outTw,          // B x 96
    int nb)
{
    const int tid  = threadIdx.x;
    const int s    = tid & 3;            // segment (joints 4s..4s+3)
    const int lane = tid & 63;
    const int quad = tid >> 2;           // 0..63 within block

    // ---- uniform T_init pieces, hoisted out of the loop ----
    float rr = init_rpy[0], pt = init_rpy[1], yw = init_rpy[2];
    float sr = __sinf(rr), cr = __cosf(rr);
    float sp = __sinf(pt), cp = __cosf(pt);
    float sy = __sinf(yw), cy = __cosf(yw);
    float i00 = cy*cp, i01 = cy*sp*sr - sy*cr, i02 = cy*sp*cr + sy*sr;
    float i10 = sy*cp, i11 = sy*sp*sr + cy*cr, i12 = sy*sp*cr - cy*sr;
    float i20 = -sp,   i21 = cp*sr,            i22 = cp*cr;
    float ip0 = init_p[0], ip1 = init_p[1], ip2 = init_p[2];

    #pragma unroll 1
    for (int t = 0; t < EPB / 64; ++t) {
        const int e = blockIdx.x * EPB + t * 64 + quad;
        if (e >= nb) break;
        const size_t g = (size_t)e * 4 + s;

        float qk[4];
        {
            float4 v = reinterpret_cast<const float4*>(q)[(size_t)e * 4 + s];
            qk[0] = v.x; qk[1] = v.y; qk[2] = v.z; qk[3] = v.w;
        }

        // ---- phase 1: serial product of my segment ----
        Mat P = buildA(twist, 4*s + 0, qk[0]);
        #pragma unroll
        for (int k = 1; k < 4; ++k)
            P = mul(P, buildA(twist, 4*s + k, qk[k]));

        // ---- inclusive Kogge-Stone scan over the quad (steps 1, 2) ----
        #pragma unroll
        for (int step = 1; step < 4; step <<= 1) {
            const bool use = (s >= step);
            const int  src = use ? lane - step : lane;
            Mat T;
            #pragma unroll
            for (int i = 0; i < 12; ++i) T.m[i] = __shfl(P.m[i], src, 64);
            Mat M = mul(T, P);
            #pragma unroll
            for (int i = 0; i < 12; ++i) P.m[i] = use ? M.m[i] : P.m[i];
        }

        // ---- exclusive prefix = entry pose for my segment ----
        Mat pose;
        {
            const int src = (s == 0) ? lane : lane - 1;
            #pragma unroll
            for (int i = 0; i < 12; ++i) pose.m[i] = __shfl(P.m[i], src, 64);
            const float id[12] = {1,0,0, 0,1,0, 0,0,1, 0,0,0};
            #pragma unroll
            for (int i = 0; i < 12; ++i) pose.m[i] = (s == 0) ? id[i] : pose.m[i];
        }

        // ---- phase 2: tw_local for my 4 joints; immediate float2 stores ----
        float2* twb = reinterpret_cast<float2*>(outTw) + g * 12;
        #pragma unroll
        for (int k = 0; k < 4; ++k) {
            const int j = 4*s + k;
            const float2* t2 = reinterpret_cast<const float2*>(twist) + 3 * j;
            float2 ta = t2[0], tb = t2[1], tc = t2[2];
            float w0 = ta.x, w1 = ta.y, w2 = tb.x;
            float v0 = tb.y, v1 = tc.x, v2 = tc.y;
            float p0 = pose.m[9], p1 = pose.m[10], p2 = pose.m[11];
            float u0 = v0 - (p1*w2 - p2*w1);
            float u1 = v1 - (p2*w0 - p0*w2);
            float u2 = v2 - (p0*w1 - p1*w0);
            float wl0 = pose.m[0]*w0 + pose.m[3]*w1 + pose.m[6]*w2;
            float wl1 = pose.m[1]*w0 + pose.m[4]*w1 + pose.m[7]*w2;
            float wl2 = pose.m[2]*w0 + pose.m[5]*w1 + pose.m[8]*w2;
            float vl0 = pose.m[0]*u0 + pose.m[3]*u1 + pose.m[6]*u2;
            float vl1 = pose.m[1]*u0 + pose.m[4]*u1 + pose.m[7]*u2;
            float vl2 = pose.m[2]*u0 + pose.m[5]*u1 + pose.m[8]*u2;
            twb[3*k+0] = make_float2(wl0, wl1);
            twb[3*k+1] = make_float2(wl2, vl0);
            twb[3*k+2] = make_float2(vl1, vl2);
            if (k < 3)
                pose = mul(pose, buildA(twist, j, qk[k]));
        }

        // ---- final: full-chain product from quad lane 3, apply T_init ----
        Mat F;
        {
            const int src = lane | 3;
            #pragma unroll
            for (int i = 0; i < 12; ++i) F.m[i] = __shfl(P.m[i], src, 64);
        }
        float r0 = (s == 0) ? F.m[0] : (s == 1) ? F.m[3] : F.m[6];
        float r1 = (s == 0) ? F.m[1] : (s == 1) ? F.m[4] : F.m[7];
        float r2 = (s == 0) ? F.m[2] : (s == 1) ? F.m[5] : F.m[8];
        float pr = (s == 0) ? F.m[9] : (s == 1) ? F.m[10] : F.m[11];
        float4 row;
        row.x = r0*i00 + r1*i10 + r2*i20;
        row.y = r0*i01 + r1*i11 + r2*i21;
        row.z = r0*i02 + r1*i12 + r2*i22;
        row.w = r0*ip0 + r1*ip1 + r2*ip2 + pr;
        if (s == 3) row = make_float4(0.f, 0.f, 0.f, 1.f);

        reinterpret_cast<float4*>(outT)[g] = row;
    }
}

extern "C" void kernel_launch(void* const* d_in, const int* in_sizes, int n_in,
                              void* d_out, int out_size, void* d_ws, size_t ws_size,
                              hipStream_t stream) {
    const float* q        = (const float*)d_in[0];
    const float* twist    = (const float*)d_in[1];
    const float* init_p   = (const float*)d_in[2];
    const float* init_rpy = (const float*)d_in[3];

    int nb = in_sizes[0] / NJ;   // B
    float* outT  = (float*)d_out;                  // B x 16 (4x4 matrices)
    float* outTw = outT + (size_t)nb * 16;         // B x 96 (Twistls)

    int blocks = (nb + EPB - 1) / EPB;             // 2048 for B=262144
    poe_fwd<<<blocks, BLK, 0, stream>>>(q, twist, init_p, init_rpy, outT, outTw, nb);
}